// Round 3
// baseline (797.212 us; speedup 1.0000x reference)
//
#include <hip/hip_runtime.h>
#include <stdint.h>

// Shapes (fixed by setup_inputs)
#define BB    4
#define CC    2
#define TT    8
#define HH    128
#define WW    128
#define NN    131072      // T*H*W = 1<<17
#define DD    512
#define PP    32
#define FF    98          // C + 3P
#define KP    104         // F padded to multiple of 8
#define MMAX  65536

// ws layout (bytes)
#define WT_OFF   0                         // KP*DD*4 = 212992
#define CIDX_OFF 212992                    // BB*MMAX*4 = 1048576
#define TAB_OFF  (CIDX_OFF + 1048576)      // 8448*4 = 33792
#define CNT_OFF  (TAB_OFF + 33792)         // BB*512*4 = 8192
#define OFFS_OFF (CNT_OFF + 8192)          // BB*512*4 = 8192
#define TOT_OFF  (OFFS_OFF + 8192)         // BB*4

// ---------------- fused: sincos tables (8448 floats) + W^T (KP*DD floats) ----------------
// tab: et[8][32] | eh[128][32] | ew[128][32]   (each row: [sin(16) | cos(16)])
__global__ void k_prep(const float* __restrict__ w, float* __restrict__ tab,
                       float* __restrict__ wt) {
    int i = blockIdx.x * 256 + threadIdx.x;
    if (i < 8448) {
        int pos, j;
        if (i < 256)            { pos = i >> 5;            j = i & 31; }
        else if (i < 256+4096)  { int ii = i - 256;        pos = ii >> 5; j = ii & 31; }
        else                    { int ii = i - 256 - 4096; pos = ii >> 5; j = ii & 31; }
        int jj = (j < 16) ? j : (j - 16);
        float omega = 1.0f / powf(10000.0f, (float)jj * (1.0f/16.0f));
        float arg = (float)pos * omega;
        tab[i] = (j < 16) ? sinf(arg) : cosf(arg);
    }
    int k = i - 8448;
    if (k >= 0 && k < KP * DD) {
        int f = k >> 9, d = k & 511;
        wt[k] = (f < FF) ? w[d * FF + f] : 0.0f;   // wt[f][d], zero-padded K rows
    }
}

// ---------------- per-block nonzero counts (256 elems/block) ----------------
__global__ void k_count(const int* __restrict__ mask, int* __restrict__ cnt) {
    int b = blockIdx.y;
    int i = blockIdx.x * 256 + threadIdx.x;
    int m = (mask[b * NN + i] != 0);
    uint64_t bal = __ballot(m);
    __shared__ int wc[4];
    int lane = threadIdx.x & 63, wv = threadIdx.x >> 6;
    if (lane == 0) wc[wv] = __popcll(bal);
    __syncthreads();
    if (threadIdx.x == 0) cnt[b * 512 + blockIdx.x] = wc[0] + wc[1] + wc[2] + wc[3];
}

// ---------------- scan 512 block-counts per batch (1 block of 512 threads) ----------------
__global__ void k_scan(const int* __restrict__ cnt, int* __restrict__ offs, int* __restrict__ tot) {
    int b = blockIdx.x, t = threadIdx.x;
    __shared__ int s[512];
    int v0 = cnt[b * 512 + t];
    s[t] = v0;
    __syncthreads();
    for (int off = 1; off < 512; off <<= 1) {
        int add = (t >= off) ? s[t - off] : 0;
        __syncthreads();
        s[t] += add;
        __syncthreads();
    }
    offs[b * 512 + t] = s[t] - v0;      // exclusive prefix
    if (t == 511) tot[b] = s[511];
}

// ---------------- order-preserving scatter of nonzero indices ----------------
// cidx[b][r] = flat voxel index of r-th nonzero (row-major order), r < MMAX.
// Slots r >= min(tot[b], MMAX) are left unwritten (GEMM gates on tot).
__global__ void k_scatter(const int* __restrict__ mask, const int* __restrict__ offs,
                          int* __restrict__ cidx) {
    int b = blockIdx.y;
    int i = blockIdx.x * 256 + threadIdx.x;
    int m = (mask[b * NN + i] != 0);
    uint64_t bal = __ballot(m);
    int lane = threadIdx.x & 63, wv = threadIdx.x >> 6;
    __shared__ int wc[4];
    if (lane == 0) wc[wv] = __popcll(bal);
    __syncthreads();
    int woff = 0;
    for (int k = 0; k < wv; ++k) woff += wc[k];
    int rank = __popcll(bal & ((1ull << lane) - 1ull));
    if (m) {
        int r = offs[b * 512 + blockIdx.x] + woff + rank;
        if (r < MMAX) cidx[b * MMAX + r] = i;
    }
}

// ---------------- fused feature-build + fp32 GEMM + pad_mask epilogue ----------------
// One block per (b, mt): builds the 64-row A tile ONCE, then loops the 8 d-tiles.
// LDS: As[KP][64] + Bs[KP][64] = 53 KB -> 3 blocks/CU. Block 256 thr, 4x4 reg tile.
__global__ __launch_bounds__(256) void k_gemm(
    const float* __restrict__ yobs, const int* __restrict__ cidx,
    const float* __restrict__ tab,  const float* __restrict__ wt,
    const float* __restrict__ bias, const int* __restrict__ tot,
    float* __restrict__ out, float* __restrict__ pm)
{
    __shared__ float As[KP][64];
    __shared__ float Bs[KP][64];
    int bid = blockIdx.x;
    int mt = bid & 1023;
    int b  = bid >> 10;
    int m0 = mt << 6;
    int tid = threadIdx.x;
    int totb = tot[b];                      // uniform scalar load

    // ---- pad_mask (no LDS dependency; tot[b] may exceed MMAX -> all valid) ----
    if (tid < 64)
        pm[(b << 16) + m0 + tid] = ((m0 + tid) >= totb) ? 1.0f : 0.0f;

    // ---- build A tile once (feat; zero rows for padding) ----
    {
        int m = tid & 63, q = tid >> 6;      // wave q handles k = q, q+4, ...
        bool val = (m0 + m) < totb;          // validity from compacted count
        int idx = 0, tt = 0, hh = 0, ww = 0;
        if (val) {
            idx = cidx[(b << 16) + m0 + m];
            tt = idx >> 14; hh = (idx >> 7) & 127; ww = idx & 127;
        }
        const float* et = tab;
        const float* eh = tab + 256;
        const float* ew = tab + 4352;
        for (int k = q; k < KP; k += 4) {
            float f = 0.0f;
            if (val) {
                if (k < 2)       f = yobs[((b * 2 + k) << 17) + idx];
                else if (k < 34) f = et[(tt << 5) + k - 2];
                else if (k < 66) f = eh[(hh << 5) + k - 34];
                else if (k < 98) f = ew[(ww << 5) + k - 66];
            }
            As[k][m] = f;                    // lanes hit distinct banks (m = lane)
        }
    }

    int tx = tid & 15, ty = tid >> 4;
    const float4* ap = (const float4*)As + ty;   // As[k][ty*4], broadcast within 16-lane groups
    const float4* bp = (const float4*)Bs + tx;   // Bs[k][tx*4], 2-way/broadcast = free

    for (int dt = 0; dt < 8; ++dt) {
        // ---- load B d-slice from pre-transposed wt[KP][DD] (float4, coalesced) ----
        for (int i = tid; i < KP * 16; i += 256) {
            int f = i >> 4, d4 = i & 15;
            *(float4*)&Bs[f][d4 << 2] = *(const float4*)&wt[(f << 9) + (dt << 6) + (d4 << 2)];
        }
        __syncthreads();                         // As ready (iter 0) + Bs ready

        float acc[4][4] = {};
        #pragma unroll 4
        for (int k = 0; k < KP; ++k) {
            float4 a  = ap[k * 16];
            float4 w4 = bp[k * 16];
            float av[4] = {a.x, a.y, a.z, a.w};
            float wv[4] = {w4.x, w4.y, w4.z, w4.w};
            #pragma unroll
            for (int i = 0; i < 4; ++i)
                #pragma unroll
                for (int j = 0; j < 4; ++j)
                    acc[i][j] = fmaf(av[i], wv[j], acc[i][j]);
        }

        float4 b4 = *(const float4*)&bias[(dt << 6) + (tx << 2)];
        float bv[4] = {b4.x, b4.y, b4.z, b4.w};
        size_t row0 = ((size_t)((b << 16) + m0 + (ty << 2))) * DD + (dt << 6) + (tx << 2);
        #pragma unroll
        for (int i = 0; i < 4; ++i) {
            float4 r;
            r.x = acc[i][0] + bv[0];
            r.y = acc[i][1] + bv[1];
            r.z = acc[i][2] + bv[2];
            r.w = acc[i][3] + bv[3];
            *(float4*)&out[row0 + (size_t)i * DD] = r;
        }
        __syncthreads();                         // guard Bs overwrite next iter
    }
}

extern "C" void kernel_launch(void* const* d_in, const int* in_sizes, int n_in,
                              void* d_out, int out_size, void* d_ws, size_t ws_size,
                              hipStream_t stream) {
    const float* yobs  = (const float*)d_in[0];
    const int*   mask  = (const int*)d_in[1];
    const float* projw = (const float*)d_in[2];
    const float* projb = (const float*)d_in[3];

    char* ws = (char*)d_ws;
    float* wt   = (float*)(ws + WT_OFF);
    int*   cidx = (int*)  (ws + CIDX_OFF);
    float* tab  = (float*)(ws + TAB_OFF);
    int*   cnt  = (int*)  (ws + CNT_OFF);
    int*   offs = (int*)  (ws + OFFS_OFF);
    int*   tot  = (int*)  (ws + TOT_OFF);

    float* cond = (float*)d_out;                           // (B, MMAX, D)
    float* pm   = (float*)d_out + (size_t)BB * MMAX * DD;  // (B, MMAX) as 0/1

    k_prep<<<(8448 + KP * DD + 255) / 256, 256, 0, stream>>>(projw, tab, wt);
    k_count<<<dim3(512, BB), 256, 0, stream>>>(mask, cnt);
    k_scan<<<BB, 512, 0, stream>>>(cnt, offs, tot);
    k_scatter<<<dim3(512, BB), 256, 0, stream>>>(mask, offs, cidx);
    k_gemm<<<BB * 1024, 256, 0, stream>>>(yobs, cidx, tab, wt, projb, tot, cond, pm);
}

// Round 4
// 720.834 us; speedup vs baseline: 1.1060x; 1.1060x over previous
//
#include <hip/hip_runtime.h>
#include <stdint.h>

// Shapes (fixed by setup_inputs)
#define BB    4
#define CC    2
#define NN    131072      // T*H*W = 1<<17
#define DD    512
#define FF    98          // C + 3P
#define K2    128         // K padded for MFMA (4 steps of 32 / 8 steps of 16)
#define MMAX  65536

// K-order (both A and B use it): k<32: et[k] | k<64: eh[k-32] | k<96: ew[k-64]
//                                k==96: val ch0 | k==97: val ch1 | k>=98: zero pad
// (orig feat order is [vals, et, eh, ew]; any consistent permutation is valid)

// ws layout (bytes), all 16B-aligned
#define BTH_OFF  0                          // DD*K2*2 = 131072
#define BTL_OFF  131072                     // 131072
#define TAB_OFF  262144                     // 8448*4 = 33792
#define CIDX_OFF 295936                     // BB*MMAX*4 = 1048576
#define CNT_OFF  1344512                    // BB*512*4 = 8192
#define OFFS_OFF 1352704                    // 8192
#define TOT_OFF  1360896                    // 16

typedef short  s16x8  __attribute__((ext_vector_type(8)));
typedef float  f32x16 __attribute__((ext_vector_type(16)));

__device__ __forceinline__ unsigned short f2bf(float x) {   // RNE f32 -> bf16 bits
    uint32_t u = __builtin_bit_cast(uint32_t, x);
    u += 0x7fffu + ((u >> 16) & 1u);
    return (unsigned short)(u >> 16);
}
__device__ __forceinline__ float bf2f(unsigned short h) {
    uint32_t u = ((uint32_t)h) << 16;
    return __builtin_bit_cast(float, u);
}

// ---------------- prep: sincos tables + hi/lo bf16 split of proj_w (reordered K) ----------------
// tab: et[8][32] | eh[128][32] | ew[128][32]   (each row: [sin(16) | cos(16)])
// bth/btl: [DD][K2] bf16 bits, bth[d][k] = hi(w[d, korig(k)]), btl = lo
__global__ void k_prep(const float* __restrict__ w, float* __restrict__ tab,
                       unsigned short* __restrict__ bth, unsigned short* __restrict__ btl) {
    int i = blockIdx.x * 256 + threadIdx.x;
    if (i < 8448) {
        int pos, j;
        if (i < 256)            { pos = i >> 5;            j = i & 31; }
        else if (i < 256+4096)  { int ii = i - 256;        pos = ii >> 5; j = ii & 31; }
        else                    { int ii = i - 256 - 4096; pos = ii >> 5; j = ii & 31; }
        int jj = (j < 16) ? j : (j - 16);
        float omega = 1.0f / powf(10000.0f, (float)jj * (1.0f/16.0f));
        float arg = (float)pos * omega;
        tab[i] = (j < 16) ? sinf(arg) : cosf(arg);
    }
    int k = i - 8448;
    if (k >= 0 && k < DD * K2) {
        int d = k >> 7, kk = k & 127;
        float v = 0.0f;
        if (kk < 96)      v = w[d * FF + kk + 2];     // pos dims
        else if (kk < 98) v = w[d * FF + (kk - 96)];  // value channels
        unsigned short h = f2bf(v);
        bth[k] = h;
        btl[k] = f2bf(v - bf2f(h));
    }
}

// ---------------- per-block nonzero counts (256 elems/block) ----------------
__global__ void k_count(const int* __restrict__ mask, int* __restrict__ cnt) {
    int b = blockIdx.y;
    int i = blockIdx.x * 256 + threadIdx.x;
    int m = (mask[b * NN + i] != 0);
    uint64_t bal = __ballot(m);
    __shared__ int wc[4];
    int lane = threadIdx.x & 63, wv = threadIdx.x >> 6;
    if (lane == 0) wc[wv] = __popcll(bal);
    __syncthreads();
    if (threadIdx.x == 0) cnt[b * 512 + blockIdx.x] = wc[0] + wc[1] + wc[2] + wc[3];
}

// ---------------- scan 512 block-counts per batch ----------------
__global__ void k_scan(const int* __restrict__ cnt, int* __restrict__ offs, int* __restrict__ tot) {
    int b = blockIdx.x, t = threadIdx.x;
    __shared__ int s[512];
    int v0 = cnt[b * 512 + t];
    s[t] = v0;
    __syncthreads();
    for (int off = 1; off < 512; off <<= 1) {
        int add = (t >= off) ? s[t - off] : 0;
        __syncthreads();
        s[t] += add;
        __syncthreads();
    }
    offs[b * 512 + t] = s[t] - v0;
    if (t == 511) tot[b] = s[511];
}

// ---------------- order-preserving scatter of nonzero indices ----------------
__global__ void k_scatter(const int* __restrict__ mask, const int* __restrict__ offs,
                          int* __restrict__ cidx) {
    int b = blockIdx.y;
    int i = blockIdx.x * 256 + threadIdx.x;
    int m = (mask[b * NN + i] != 0);
    uint64_t bal = __ballot(m);
    int lane = threadIdx.x & 63, wv = threadIdx.x >> 6;
    __shared__ int wc[4];
    if (lane == 0) wc[wv] = __popcll(bal);
    __syncthreads();
    int woff = 0;
    for (int k = 0; k < wv; ++k) woff += wc[k];
    int rank = __popcll(bal & ((1ull << lane) - 1ull));
    if (m) {
        int r = offs[b * 512 + blockIdx.x] + woff + rank;
        if (r < MMAX) cidx[b * MMAX + r] = i;
    }
}

// ---------------- fused feature-build + split-bf16 MFMA GEMM ----------------
// Block = (b, mt): 64 rows. A (64x128) built once in swizzled LDS (hi+lo),
// A-frags hoisted to VGPRs, then 8 d-tiles of 64 cols; B-frags loaded
// global->VGPR (L2-resident, no barriers in the dt loop).
// Wave w: rows (w>>1)*32, cols (w&1)*32 of the 64x64 (per-dt) tile.
// mfma_f32_32x32x16_bf16: A lane l: row=l&31, k=8*(l>>5)+j; B: col=l&31, same k;
// D: col=l&31, row=(reg&3)+8*(reg>>2)+4*(l>>5)   [guide §3, m74/m101]
__global__ __launch_bounds__(256) void k_gemm(
    const float* __restrict__ yobs, const int* __restrict__ cidx,
    const float* __restrict__ tab,
    const unsigned short* __restrict__ bth, const unsigned short* __restrict__ btl,
    const float* __restrict__ bias, const int* __restrict__ tot,
    float* __restrict__ out, float* __restrict__ pm)
{
    __shared__ unsigned short As[2][64 * 128];   // [hi|lo][row][k], 32 KB, XOR-swizzled
    int bid = blockIdx.x;
    int mt = bid & 1023;
    int b  = bid >> 10;
    int m0 = mt << 6;
    int tid = threadIdx.x;
    int totb = tot[b];

    if (tid < 64)
        pm[(b << 16) + m0 + tid] = ((m0 + tid) >= totb) ? 1.0f : 0.0f;

    // ---- build A tile: 4 threads per row, thread s covers k = s*32..s*32+31 ----
    {
        int r = tid >> 2, s = tid & 3;
        bool val = (m0 + r) < totb;
        float v[32];
        #pragma unroll
        for (int j = 0; j < 32; ++j) v[j] = 0.0f;
        if (val) {
            int idx = cidx[(b << 16) + m0 + r];
            if (s < 3) {
                int p = (s == 0) ? (idx >> 14) : (s == 1) ? ((idx >> 7) & 127) : (idx & 127);
                const float* base = tab + ((s == 0) ? 0 : (s == 1) ? 256 : 4352) + (p << 5);
                const float4* b4 = (const float4*)base;        // 128B-aligned rows
                #pragma unroll
                for (int q = 0; q < 8; ++q) {
                    float4 f = b4[q];
                    v[4*q] = f.x; v[4*q+1] = f.y; v[4*q+2] = f.z; v[4*q+3] = f.w;
                }
            } else {
                v[0] = yobs[((size_t)(b * 2) << 17) + idx];
                v[1] = yobs[((size_t)(b * 2 + 1) << 17) + idx];
            }
        }
        uint32_t rowbase = (uint32_t)r * 256u;
        uint32_t M = (uint32_t)(((r & 7) << 4) ^ (((r >> 3) & 1) << 7));
        #pragma unroll
        for (int c = 0; c < 4; ++c) {
            uint32_t hp[4], lp[4];
            #pragma unroll
            for (int q = 0; q < 4; ++q) {
                float a0 = v[c*8 + 2*q], a1 = v[c*8 + 2*q + 1];
                unsigned short h0 = f2bf(a0), h1 = f2bf(a1);
                unsigned short l0 = f2bf(a0 - bf2f(h0)), l1 = f2bf(a1 - bf2f(h1));
                hp[q] = (uint32_t)h0 | ((uint32_t)h1 << 16);
                lp[q] = (uint32_t)l0 | ((uint32_t)l1 << 16);
            }
            uint32_t byt = ((uint32_t)(s * 64 + c * 16)) ^ M;
            *(uint4*)((char*)&As[0][0] + rowbase + byt) = make_uint4(hp[0], hp[1], hp[2], hp[3]);
            *(uint4*)((char*)&As[1][0] + rowbase + byt) = make_uint4(lp[0], lp[1], lp[2], lp[3]);
        }
    }
    __syncthreads();

    int w = tid >> 6, l = tid & 63;
    int wr = w >> 1, wc = w & 1;
    int lrow = l & 31, lh = l >> 5;

    // ---- hoist A-frags (read once; swizzle makes this ~2-way = free) ----
    int arow = wr * 32 + lrow;
    uint32_t abase = (uint32_t)arow * 256u;
    uint32_t AM = (uint32_t)(((arow & 7) << 4) ^ (((arow >> 3) & 1) << 7));
    s16x8 afh[8], afl[8];
    #pragma unroll
    for (int ks = 0; ks < 8; ++ks) {
        uint32_t byt = ((uint32_t)(ks * 32 + lh * 16)) ^ AM;
        afh[ks] = *(const s16x8*)((char*)&As[0][0] + abase + byt);
        afl[ks] = *(const s16x8*)((char*)&As[1][0] + abase + byt);
    }

    // ---- per-lane B base: col = wc*32+lrow (within d-tile), k0 = 8*lh ----
    const unsigned short* bhp = bth + ((wc * 32 + lrow) << 7) + (lh << 3);
    const unsigned short* blp = btl + ((wc * 32 + lrow) << 7) + (lh << 3);

    for (int dt = 0; dt < 8; ++dt) {
        const unsigned short* bh = bhp + (dt << 13);   // dt*64*128
        const unsigned short* bl = blp + (dt << 13);
        s16x8 bfh[8], bfl[8];
        #pragma unroll
        for (int ks = 0; ks < 8; ++ks) {
            bfh[ks] = *(const s16x8*)(bh + ks * 16);
            bfl[ks] = *(const s16x8*)(bl + ks * 16);
        }
        f32x16 acc = {};
        #pragma unroll
        for (int ks = 0; ks < 8; ++ks) {
            acc = __builtin_amdgcn_mfma_f32_32x32x16_bf16(afh[ks], bfh[ks], acc, 0, 0, 0);
            acc = __builtin_amdgcn_mfma_f32_32x32x16_bf16(afh[ks], bfl[ks], acc, 0, 0, 0);
            acc = __builtin_amdgcn_mfma_f32_32x32x16_bf16(afl[ks], bfh[ks], acc, 0, 0, 0);
        }
        int col = (dt << 6) + wc * 32 + lrow;
        float bv = bias[col];
        size_t obase = ((size_t)((b << 16) + m0 + wr * 32 + 4 * lh)) * DD + col;
        #pragma unroll
        for (int reg = 0; reg < 16; ++reg) {
            int rrow = (reg & 3) + 8 * (reg >> 2);
            out[obase + (size_t)rrow * DD] = acc[reg] + bv;
        }
    }
}

extern "C" void kernel_launch(void* const* d_in, const int* in_sizes, int n_in,
                              void* d_out, int out_size, void* d_ws, size_t ws_size,
                              hipStream_t stream) {
    const float* yobs  = (const float*)d_in[0];
    const int*   mask  = (const int*)d_in[1];
    const float* projw = (const float*)d_in[2];
    const float* projb = (const float*)d_in[3];

    char* ws = (char*)d_ws;
    unsigned short* bth = (unsigned short*)(ws + BTH_OFF);
    unsigned short* btl = (unsigned short*)(ws + BTL_OFF);
    float* tab  = (float*)(ws + TAB_OFF);
    int*   cidx = (int*)  (ws + CIDX_OFF);
    int*   cnt  = (int*)  (ws + CNT_OFF);
    int*   offs = (int*)  (ws + OFFS_OFF);
    int*   tot  = (int*)  (ws + TOT_OFF);

    float* cond = (float*)d_out;                           // (B, MMAX, D)
    float* pm   = (float*)d_out + (size_t)BB * MMAX * DD;  // (B, MMAX) as 0/1

    k_prep<<<(8448 + DD * K2 + 255) / 256, 256, 0, stream>>>(projw, tab, bth, btl);
    k_count<<<dim3(512, BB), 256, 0, stream>>>(mask, cnt);
    k_scan<<<BB, 512, 0, stream>>>(cnt, offs, tot);
    k_scatter<<<dim3(512, BB), 256, 0, stream>>>(mask, offs, cidx);
    k_gemm<<<BB * 1024, 256, 0, stream>>>(yobs, cidx, tab, bth, btl, projb, tot, cond, pm);
}